// Round 1
// baseline (571.654 us; speedup 1.0000x reference)
//
#include <hip/hip_runtime.h>
#include <math.h>

// Problem constants
#define HH_ 12
#define DD_ 64
#define CC_ 768
#define NN_ 1024
#define BB_ 4
#define M_TOT 4096                 // B*N
#define BHND 3145728               // B*H*N*D floats per q/k/v tensor

// ---------------------------------------------------------------------------
// GEMM: out = A(M x 768) * W^T   (W is Wn x 768, row-major => K-contiguous)
// BM=128, BN=64, BK=16, 256 threads, 8x4 micro-tile.
// MODE 0: scatter into qkv [3][B][H][N][D]   (out = base of q)
// MODE 1: direct out[m][c] + bias[c]
// ---------------------------------------------------------------------------
template <int MODE>
__global__ __launch_bounds__(256) void gemm_kernel(const float* __restrict__ A,
                                                   const float* __restrict__ W,
                                                   const float* __restrict__ bias,
                                                   float* __restrict__ out) {
    __shared__ float As[16][132];   // [k][m], padded
    __shared__ float Bs[16][68];    // [k][c], padded

    const int tid = threadIdx.x;
    const int m0 = blockIdx.y * 128;
    const int c0 = blockIdx.x * 64;

    const int ty = tid >> 4;         // 0..15
    const int tx = tid & 15;         // 0..15
    const int row0 = ty * 8;
    const int col0 = tx * 4;

    const int la_row = tid >> 2;          // 0..63
    const int la_k4 = (tid & 3) * 4;      // 0,4,8,12

    float acc[8][4];
#pragma unroll
    for (int i = 0; i < 8; ++i)
#pragma unroll
        for (int j = 0; j < 4; ++j) acc[i][j] = 0.0f;

    for (int k0 = 0; k0 < 768; k0 += 16) {
        __syncthreads();
        // Stage A tile (128x16) transposed -> As[k][m]
#pragma unroll
        for (int j = 0; j < 2; ++j) {
            const int r = la_row + j * 64;
            const float4 av = *(const float4*)(A + (size_t)(m0 + r) * 768 + k0 + la_k4);
            As[la_k4 + 0][r] = av.x;
            As[la_k4 + 1][r] = av.y;
            As[la_k4 + 2][r] = av.z;
            As[la_k4 + 3][r] = av.w;
        }
        // Stage W tile (64x16) transposed -> Bs[k][c]
        {
            const int c = tid >> 2;
            const float4 wv = *(const float4*)(W + (size_t)(c0 + c) * 768 + k0 + la_k4);
            Bs[la_k4 + 0][c] = wv.x;
            Bs[la_k4 + 1][c] = wv.y;
            Bs[la_k4 + 2][c] = wv.z;
            Bs[la_k4 + 3][c] = wv.w;
        }
        __syncthreads();
#pragma unroll
        for (int kk = 0; kk < 16; ++kk) {
            const float4 a0 = *(const float4*)&As[kk][row0];
            const float4 a1 = *(const float4*)&As[kk][row0 + 4];
            const float4 bv = *(const float4*)&Bs[kk][col0];
            const float ar[8] = {a0.x, a0.y, a0.z, a0.w, a1.x, a1.y, a1.z, a1.w};
            const float br[4] = {bv.x, bv.y, bv.z, bv.w};
#pragma unroll
            for (int i = 0; i < 8; ++i)
#pragma unroll
                for (int j = 0; j < 4; ++j) acc[i][j] += ar[i] * br[j];
        }
    }

    if (MODE == 0) {
        // c_glob = c0 + col0 + j ; all 64 cols of this block share (s, h)
        const int s = c0 / 768;
        const int h = (c0 % 768) / 64;
        float* dst = out + (size_t)s * BHND;
#pragma unroll
        for (int i = 0; i < 8; ++i) {
            const int m = m0 + row0 + i;
            const int b = m >> 10;
            const int n = m & 1023;
            float4 v;
            v.x = acc[i][0]; v.y = acc[i][1]; v.z = acc[i][2]; v.w = acc[i][3];
            *(float4*)(dst + ((size_t)(b * HH_ + h) * NN_ + n) * 64 + col0) = v;
        }
    } else {
        const float4 bv = *(const float4*)(bias + c0 + col0);
#pragma unroll
        for (int i = 0; i < 8; ++i) {
            const int m = m0 + row0 + i;
            float4 v;
            v.x = acc[i][0] + bv.x;
            v.y = acc[i][1] + bv.y;
            v.z = acc[i][2] + bv.z;
            v.w = acc[i][3] + bv.w;
            *(float4*)(out + (size_t)m * 768 + c0 + col0) = v;
        }
    }
}

// ---------------------------------------------------------------------------
// Flash attention with relative-position bias, fp32.
// Block = (b,h, 64-row Q tile), 256 threads (16x16, 4x4 micro).
// ---------------------------------------------------------------------------
__global__ __launch_bounds__(256) void attn_kernel(const float* __restrict__ q,
                                                   const float* __restrict__ k,
                                                   const float* __restrict__ v,
                                                   const float* __restrict__ rel_table,
                                                   float* __restrict__ attout) {
    __shared__ float Qt[64][68];   // [d][r]
    __shared__ float Kt[64][68];   // [d][c]
    __shared__ float Vs[64][68];   // [c][d]
    __shared__ float Ps[64][68];   // [c][r]
    __shared__ float tbl[129];

    const int tid = threadIdx.x;
    const int bh = blockIdx.y;
    const int b = bh / HH_;
    const int h = bh % HH_;
    const int q0 = blockIdx.x * 64;

    const size_t base = (size_t)bh * NN_ * 64;
    const float* qp = q + base;
    const float* kp = k + base;
    const float* vp = v + base;

    if (tid < 129) tbl[tid] = rel_table[tid * HH_ + h];

    // Load Q tile transposed
#pragma unroll
    for (int j = 0; j < 4; ++j) {
        const int idx = tid + j * 256;
        const int r = idx >> 4;
        const int d4 = (idx & 15) * 4;
        const float4 qv = *(const float4*)(qp + (size_t)(q0 + r) * 64 + d4);
        Qt[d4 + 0][r] = qv.x;
        Qt[d4 + 1][r] = qv.y;
        Qt[d4 + 2][r] = qv.z;
        Qt[d4 + 3][r] = qv.w;
    }

    const int ty = tid >> 4;   // row group 0..15
    const int tx = tid & 15;   // col group 0..15

    float m_run[4], l_run[4], O[4][4];
#pragma unroll
    for (int i = 0; i < 4; ++i) {
        m_run[i] = -INFINITY;
        l_run[i] = 0.0f;
#pragma unroll
        for (int j = 0; j < 4; ++j) O[i][j] = 0.0f;
    }

    const float scale = 0.125f;            // 64^-0.5
    const float LOG2E = 1.44269504f;

    for (int t = 0; t < 16; ++t) {
        const int k0 = t * 64;
        __syncthreads();   // prev PV done before overwriting Kt/Vs/Ps
        // Stage K (transposed) and V (direct)
#pragma unroll
        for (int j = 0; j < 4; ++j) {
            const int idx = tid + j * 256;
            const int r = idx >> 4;
            const int d4 = (idx & 15) * 4;
            const float4 kv = *(const float4*)(kp + (size_t)(k0 + r) * 64 + d4);
            Kt[d4 + 0][r] = kv.x;
            Kt[d4 + 1][r] = kv.y;
            Kt[d4 + 2][r] = kv.z;
            Kt[d4 + 3][r] = kv.w;
            const float4 vv = *(const float4*)(vp + (size_t)(k0 + r) * 64 + d4);
            *(float4*)&Vs[r][d4] = vv;
        }
        __syncthreads();

        // S = Q K^T
        float s[4][4];
#pragma unroll
        for (int i = 0; i < 4; ++i)
#pragma unroll
            for (int j = 0; j < 4; ++j) s[i][j] = 0.0f;

        for (int d = 0; d < 64; ++d) {
            const float4 a = *(const float4*)&Qt[d][ty * 4];
            const float4 bb = *(const float4*)&Kt[d][tx * 4];
            const float ar[4] = {a.x, a.y, a.z, a.w};
            const float br[4] = {bb.x, bb.y, bb.z, bb.w};
#pragma unroll
            for (int i = 0; i < 4; ++i)
#pragma unroll
                for (int j = 0; j < 4; ++j) s[i][j] += ar[i] * br[j];
        }

        // scale + relative position bias
#pragma unroll
        for (int i = 0; i < 4; ++i) {
            const int rg = q0 + ty * 4 + i;
#pragma unroll
            for (int j = 0; j < 4; ++j) {
                const int cg = k0 + tx * 4 + j;
                int off = cg - rg + 64;
                off = off < 0 ? 0 : (off > 128 ? 128 : off);
                s[i][j] = s[i][j] * scale + tbl[off];
            }
        }

        // online softmax update
#pragma unroll
        for (int i = 0; i < 4; ++i) {
            float mx = fmaxf(fmaxf(s[i][0], s[i][1]), fmaxf(s[i][2], s[i][3]));
#pragma unroll
            for (int o = 1; o < 16; o <<= 1) mx = fmaxf(mx, __shfl_xor(mx, o));
            const float m_new = fmaxf(m_run[i], mx);
            const float alpha = exp2f((m_run[i] - m_new) * LOG2E);
            m_run[i] = m_new;
            float rs = 0.0f;
#pragma unroll
            for (int j = 0; j < 4; ++j) {
                const float p = exp2f((s[i][j] - m_new) * LOG2E);
                s[i][j] = p;
                rs += p;
            }
#pragma unroll
            for (int o = 1; o < 16; o <<= 1) rs += __shfl_xor(rs, o);
            l_run[i] = l_run[i] * alpha + rs;
#pragma unroll
            for (int j = 0; j < 4; ++j) O[i][j] *= alpha;
        }

        // stage P transposed: Ps[c][r]
#pragma unroll
        for (int i = 0; i < 4; ++i)
#pragma unroll
            for (int j = 0; j < 4; ++j) Ps[tx * 4 + j][ty * 4 + i] = s[i][j];

        __syncthreads();

        // O += P V
        for (int c = 0; c < 64; ++c) {
            const float4 a = *(const float4*)&Ps[c][ty * 4];
            const float4 vv = *(const float4*)&Vs[c][tx * 4];
            const float ar[4] = {a.x, a.y, a.z, a.w};
            const float vr[4] = {vv.x, vv.y, vv.z, vv.w};
#pragma unroll
            for (int i = 0; i < 4; ++i)
#pragma unroll
                for (int j = 0; j < 4; ++j) O[i][j] += ar[i] * vr[j];
        }
    }

    // normalize and write attout [b][n][h*64+d]
#pragma unroll
    for (int i = 0; i < 4; ++i) {
        const float inv = 1.0f / l_run[i];
        const int n = q0 + ty * 4 + i;
        float4 ov;
        ov.x = O[i][0] * inv;
        ov.y = O[i][1] * inv;
        ov.z = O[i][2] * inv;
        ov.w = O[i][3] * inv;
        *(float4*)(attout + ((size_t)b * NN_ + n) * 768 + h * 64 + tx * 4) = ov;
    }
}

// ---------------------------------------------------------------------------
extern "C" void kernel_launch(void* const* d_in, const int* in_sizes, int n_in,
                              void* d_out, int out_size, void* d_ws, size_t ws_size,
                              hipStream_t stream) {
    const float* x = (const float*)d_in[0];
    const float* qkv_w = (const float*)d_in[1];
    const float* proj_w = (const float*)d_in[2];
    const float* proj_b = (const float*)d_in[3];
    const float* rel_table = (const float*)d_in[4];

    float* ws = (float*)d_ws;
    float* q = ws;                       // [B][H][N][D]
    float* k = ws + (size_t)BHND;
    float* v = ws + (size_t)2 * BHND;
    float* attout = ws + (size_t)3 * BHND;   // [B][N][C]

    // 1) QKV projection, scattered into q/k/v
    dim3 g1(36, 32);   // 2304/64 x 4096/128
    gemm_kernel<0><<<g1, 256, 0, stream>>>(x, qkv_w, nullptr, q);

    // 2) attention
    dim3 g2(16, 48);   // N/64 x B*H
    attn_kernel<<<g2, 256, 0, stream>>>(q, k, v, rel_table, attout);

    // 3) output projection + bias
    dim3 g3(12, 32);   // 768/64 x 4096/128
    gemm_kernel<1><<<g3, 256, 0, stream>>>(attout, proj_w, proj_b, (float*)d_out);
}

// Round 2
// 452.316 us; speedup vs baseline: 1.2638x; 1.2638x over previous
//
#include <hip/hip_runtime.h>
#include <math.h>

// Problem constants
#define HH_ 12
#define NN_ 1024
#define BHND 3145728   // 48*1024*64 floats per q/k/v tensor

typedef __attribute__((ext_vector_type(8))) short bf16x8;
typedef __attribute__((ext_vector_type(4))) float f32x4;

__device__ inline unsigned short f32_to_bf16_rtn(float f) {
    unsigned int u = __builtin_bit_cast(unsigned int, f);
    unsigned int r = (u + 0x7FFFu + ((u >> 16) & 1u)) >> 16;
    return (unsigned short)r;
}
__device__ inline float bf16_to_f32(unsigned short h) {
    unsigned int u = ((unsigned int)h) << 16;
    return __builtin_bit_cast(float, u);
}

// ---------------------------------------------------------------------------
// Split-bf16 MFMA GEMM: C = A(Mx768) * W^T, W row-major [N][768].
// Tile 128x128, BK=32, 4 waves (2x2), each wave 64x64 (4x4 frags 16x16).
// a*b ~= a_hi*b_hi + a_hi*b_lo + a_lo*b_hi  (3 MFMAs per product term).
// LDS is fragment-linear: chunk[tile][lane][16B], writer lane == reader lane,
// so ds_write_b128 / ds_read_b128 are lane-linear -> conflict-free.
// MODE 0: scatter into q/k/v [3][B][H][N][D] (out = q base)
// MODE 1: out[m][c] = acc + bias[c]
// ---------------------------------------------------------------------------
template <int MODE>
__global__ __launch_bounds__(256) void gemm_split(const float* __restrict__ A,
                                                  const float* __restrict__ W,
                                                  const float* __restrict__ bias,
                                                  float* __restrict__ out) {
    // [isB][plane(hi/lo)][tile 0..7][lane*8 shorts]  = 32 chunks x 1KB = 32KB
    __shared__ __align__(16) unsigned short smem[2][2][8][512];

    const int tid = threadIdx.x;
    const int wave = tid >> 6;
    const int lane = tid & 63;
    const int g = lane >> 4;      // k-block 0..3 (8 consecutive k each)
    const int c = lane & 15;      // row-in-tile (A) / col-in-frag (B)

    const int m0 = blockIdx.y * 128;
    const int c0 = blockIdx.x * 128;

    const int wm = wave >> 1, wn = wave & 1;

    f32x4 acc[4][4];
#pragma unroll
    for (int i = 0; i < 4; ++i)
#pragma unroll
        for (int j = 0; j < 4; ++j) acc[i][j] = (f32x4)(0.0f);

    // staging role: waves 0,1 -> A tiles 0-3 / 4-7 ; waves 2,3 -> B tiles
    const int st_isB = wave >> 1;
    const int st_tbase = (wave & 1) * 4;
    const float* st_src = st_isB ? W : A;
    const int st_row0 = (st_isB ? c0 : m0) + c;

    for (int k0 = 0; k0 < 768; k0 += 32) {
        __syncthreads();   // previous step's frag reads complete
#pragma unroll
        for (int t = 0; t < 4; ++t) {
            const int tile = st_tbase + t;
            const float* p = st_src + (size_t)(st_row0 + tile * 16) * 768 + k0 + g * 8;
            const float4 v0 = *(const float4*)p;
            const float4 v1 = *(const float4*)(p + 4);
            const float f[8] = {v0.x, v0.y, v0.z, v0.w, v1.x, v1.y, v1.z, v1.w};
            bf16x8 vh, vl;
#pragma unroll
            for (int j = 0; j < 8; ++j) {
                const unsigned short h = f32_to_bf16_rtn(f[j]);
                const unsigned short l = f32_to_bf16_rtn(f[j] - bf16_to_f32(h));
                vh[j] = (short)h;
                vl[j] = (short)l;
            }
            *(bf16x8*)&smem[st_isB][0][tile][lane * 8] = vh;
            *(bf16x8*)&smem[st_isB][1][tile][lane * 8] = vl;
        }
        __syncthreads();   // staging visible to all waves

        bf16x8 a_h[4], a_l[4], b_h[4], b_l[4];
#pragma unroll
        for (int i = 0; i < 4; ++i) {
            a_h[i] = *(const bf16x8*)&smem[0][0][wm * 4 + i][lane * 8];
            a_l[i] = *(const bf16x8*)&smem[0][1][wm * 4 + i][lane * 8];
            b_h[i] = *(const bf16x8*)&smem[1][0][wn * 4 + i][lane * 8];
            b_l[i] = *(const bf16x8*)&smem[1][1][wn * 4 + i][lane * 8];
        }
#pragma unroll
        for (int i = 0; i < 4; ++i)
#pragma unroll
            for (int j = 0; j < 4; ++j) {
                acc[i][j] = __builtin_amdgcn_mfma_f32_16x16x32_bf16(a_h[i], b_h[j], acc[i][j], 0, 0, 0);
                acc[i][j] = __builtin_amdgcn_mfma_f32_16x16x32_bf16(a_h[i], b_l[j], acc[i][j], 0, 0, 0);
                acc[i][j] = __builtin_amdgcn_mfma_f32_16x16x32_bf16(a_l[i], b_h[j], acc[i][j], 0, 0, 0);
            }
    }

    // Epilogue. D-frag: row m = base + g*4 + r, col = base + c.
    if (MODE == 0) {
        const int b = m0 >> 10;
#pragma unroll
        for (int i = 0; i < 4; ++i) {
#pragma unroll
            for (int j = 0; j < 4; ++j) {
                const int cg = c0 + wn * 64 + j * 16;     // frag col base in [0,2304)
                const int s = cg / 768;                   // q/k/v selector
                const int h = (cg % 768) / 64;
                const int dbase = (cg % 64) + c;
                float* dst = out + (size_t)s * BHND + (size_t)(b * HH_ + h) * NN_ * 64;
                const int mbase = m0 + wm * 64 + i * 16 + g * 4;
#pragma unroll
                for (int r = 0; r < 4; ++r) {
                    const int n = (mbase + r) & 1023;
                    dst[(size_t)n * 64 + dbase] = acc[i][j][r];
                }
            }
        }
    } else {
        const int mbase = m0 + wm * 64 + g * 4;
#pragma unroll
        for (int i = 0; i < 4; ++i) {
#pragma unroll
            for (int j = 0; j < 4; ++j) {
                const int cg = c0 + wn * 64 + j * 16 + c;
                const float bv = bias[cg];
#pragma unroll
                for (int r = 0; r < 4; ++r) {
                    const int m = mbase + i * 16 + r;
                    out[(size_t)m * 768 + cg] = acc[i][j][r] + bv;
                }
            }
        }
    }
}

// ---------------------------------------------------------------------------
// Flash attention with relative-position bias, fp32 (unchanged from round 1).
// ---------------------------------------------------------------------------
__global__ __launch_bounds__(256) void attn_kernel(const float* __restrict__ q,
                                                   const float* __restrict__ k,
                                                   const float* __restrict__ v,
                                                   const float* __restrict__ rel_table,
                                                   float* __restrict__ attout) {
    __shared__ float Qt[64][68];   // [d][r]
    __shared__ float Kt[64][68];   // [d][c]
    __shared__ float Vs[64][68];   // [c][d]
    __shared__ float Ps[64][68];   // [c][r]
    __shared__ float tbl[129];

    const int tid = threadIdx.x;
    const int bh = blockIdx.y;
    const int b = bh / HH_;
    const int h = bh % HH_;
    const int q0 = blockIdx.x * 64;

    const size_t base = (size_t)bh * NN_ * 64;
    const float* qp = q + base;
    const float* kp = k + base;
    const float* vp = v + base;

    if (tid < 129) tbl[tid] = rel_table[tid * HH_ + h];

#pragma unroll
    for (int j = 0; j < 4; ++j) {
        const int idx = tid + j * 256;
        const int r = idx >> 4;
        const int d4 = (idx & 15) * 4;
        const float4 qv = *(const float4*)(qp + (size_t)(q0 + r) * 64 + d4);
        Qt[d4 + 0][r] = qv.x;
        Qt[d4 + 1][r] = qv.y;
        Qt[d4 + 2][r] = qv.z;
        Qt[d4 + 3][r] = qv.w;
    }

    const int ty = tid >> 4;
    const int tx = tid & 15;

    float m_run[4], l_run[4], O[4][4];
#pragma unroll
    for (int i = 0; i < 4; ++i) {
        m_run[i] = -INFINITY;
        l_run[i] = 0.0f;
#pragma unroll
        for (int j = 0; j < 4; ++j) O[i][j] = 0.0f;
    }

    const float scale = 0.125f;
    const float LOG2E = 1.44269504f;

    for (int t = 0; t < 16; ++t) {
        const int k0 = t * 64;
        __syncthreads();
#pragma unroll
        for (int j = 0; j < 4; ++j) {
            const int idx = tid + j * 256;
            const int r = idx >> 4;
            const int d4 = (idx & 15) * 4;
            const float4 kv = *(const float4*)(kp + (size_t)(k0 + r) * 64 + d4);
            Kt[d4 + 0][r] = kv.x;
            Kt[d4 + 1][r] = kv.y;
            Kt[d4 + 2][r] = kv.z;
            Kt[d4 + 3][r] = kv.w;
            const float4 vv = *(const float4*)(vp + (size_t)(k0 + r) * 64 + d4);
            *(float4*)&Vs[r][d4] = vv;
        }
        __syncthreads();

        float s[4][4];
#pragma unroll
        for (int i = 0; i < 4; ++i)
#pragma unroll
            for (int j = 0; j < 4; ++j) s[i][j] = 0.0f;

        for (int d = 0; d < 64; ++d) {
            const float4 a = *(const float4*)&Qt[d][ty * 4];
            const float4 bb = *(const float4*)&Kt[d][tx * 4];
            const float ar[4] = {a.x, a.y, a.z, a.w};
            const float br[4] = {bb.x, bb.y, bb.z, bb.w};
#pragma unroll
            for (int i = 0; i < 4; ++i)
#pragma unroll
                for (int j = 0; j < 4; ++j) s[i][j] += ar[i] * br[j];
        }

#pragma unroll
        for (int i = 0; i < 4; ++i) {
            const int rg = q0 + ty * 4 + i;
#pragma unroll
            for (int j = 0; j < 4; ++j) {
                const int cg = k0 + tx * 4 + j;
                int off = cg - rg + 64;
                off = off < 0 ? 0 : (off > 128 ? 128 : off);
                s[i][j] = s[i][j] * scale + tbl[off];
            }
        }

#pragma unroll
        for (int i = 0; i < 4; ++i) {
            float mx = fmaxf(fmaxf(s[i][0], s[i][1]), fmaxf(s[i][2], s[i][3]));
#pragma unroll
            for (int o = 1; o < 16; o <<= 1) mx = fmaxf(mx, __shfl_xor(mx, o));
            const float m_new = fmaxf(m_run[i], mx);
            const float alpha = exp2f((m_run[i] - m_new) * LOG2E);
            m_run[i] = m_new;
            float rs = 0.0f;
#pragma unroll
            for (int j = 0; j < 4; ++j) {
                const float p = exp2f((s[i][j] - m_new) * LOG2E);
                s[i][j] = p;
                rs += p;
            }
#pragma unroll
            for (int o = 1; o < 16; o <<= 1) rs += __shfl_xor(rs, o);
            l_run[i] = l_run[i] * alpha + rs;
#pragma unroll
            for (int j = 0; j < 4; ++j) O[i][j] *= alpha;
        }

#pragma unroll
        for (int i = 0; i < 4; ++i)
#pragma unroll
            for (int j = 0; j < 4; ++j) Ps[tx * 4 + j][ty * 4 + i] = s[i][j];

        __syncthreads();

        for (int cc = 0; cc < 64; ++cc) {
            const float4 a = *(const float4*)&Ps[cc][ty * 4];
            const float4 vv = *(const float4*)&Vs[cc][tx * 4];
            const float ar[4] = {a.x, a.y, a.z, a.w};
            const float vr[4] = {vv.x, vv.y, vv.z, vv.w};
#pragma unroll
            for (int i = 0; i < 4; ++i)
#pragma unroll
                for (int j = 0; j < 4; ++j) O[i][j] += ar[i] * vr[j];
        }
    }

#pragma unroll
    for (int i = 0; i < 4; ++i) {
        const float inv = 1.0f / l_run[i];
        const int n = q0 + ty * 4 + i;
        float4 ov;
        ov.x = O[i][0] * inv;
        ov.y = O[i][1] * inv;
        ov.z = O[i][2] * inv;
        ov.w = O[i][3] * inv;
        *(float4*)(attout + ((size_t)b * NN_ + n) * 768 + h * 64 + tx * 4) = ov;
    }
}

// ---------------------------------------------------------------------------
extern "C" void kernel_launch(void* const* d_in, const int* in_sizes, int n_in,
                              void* d_out, int out_size, void* d_ws, size_t ws_size,
                              hipStream_t stream) {
    const float* x = (const float*)d_in[0];
    const float* qkv_w = (const float*)d_in[1];
    const float* proj_w = (const float*)d_in[2];
    const float* proj_b = (const float*)d_in[3];
    const float* rel_table = (const float*)d_in[4];

    float* ws = (float*)d_ws;
    float* q = ws;                           // [B][H][N][D]
    float* k = ws + (size_t)BHND;
    float* v = ws + (size_t)2 * BHND;
    float* attout = ws + (size_t)3 * BHND;   // [B][N][C]

    // 1) QKV projection (split-bf16 MFMA), scattered into q/k/v
    dim3 g1(18, 32);   // 2304/128 x 4096/128
    gemm_split<0><<<g1, 256, 0, stream>>>(x, qkv_w, nullptr, q);

    // 2) attention (fp32, unchanged)
    dim3 g2(16, 48);   // N/64 x B*H
    attn_kernel<<<g2, 256, 0, stream>>>(q, k, v, rel_table, attout);

    // 3) output projection + bias (split-bf16 MFMA)
    dim3 g3(6, 32);    // 768/128 x 4096/128
    gemm_split<1><<<g3, 256, 0, stream>>>(attout, proj_w, proj_b, (float*)d_out);
}

// Round 3
// 293.536 us; speedup vs baseline: 1.9475x; 1.5409x over previous
//
#include <hip/hip_runtime.h>
#include <math.h>

#define HH 12
#define NN 1024

typedef unsigned int u32;
typedef unsigned short u16;
typedef __attribute__((ext_vector_type(8))) short bf16x8;
typedef __attribute__((ext_vector_type(4))) float f32x4;
typedef __attribute__((ext_vector_type(4))) unsigned short u16x4;

#define QSCALE 0.18033688f   // 0.125 * log2(e): folded scale + base-2 softmax

__device__ __forceinline__ u16 bf16_rtn(float f) {
    u32 u = __builtin_bit_cast(u32, f);
    return (u16)((u + 0x7FFFu + ((u >> 16) & 1u)) >> 16);
}
__device__ __forceinline__ float bf16_up(u16 h) {
    u32 u = ((u32)h) << 16;
    return __builtin_bit_cast(float, u);
}
// async global->LDS, 16B per lane, dest = uniform base + lane*16
__device__ __forceinline__ void gld_lds16(const void* g, void* l) {
    __builtin_amdgcn_global_load_lds(
        (const __attribute__((address_space(1))) u32*)(unsigned long long)g,
        (__attribute__((address_space(3))) u32*)(u32)(unsigned long long)l,
        16, 0, 0);
}

// ---------------------------------------------------------------------------
// One-time f32 -> (hi,lo) bf16 split, rtn both planes (err ~2^-18)
// ---------------------------------------------------------------------------
__global__ __launch_bounds__(256) void presplit(const float* __restrict__ in,
                                                u16* __restrict__ hi, u16* __restrict__ lo,
                                                int n4) {
    int i = blockIdx.x * 256 + threadIdx.x;
    if (i >= n4) return;
    float4 v = ((const float4*)in)[i];
    float f[4] = {v.x, v.y, v.z, v.w};
    u16x4 h, l;
#pragma unroll
    for (int j = 0; j < 4; ++j) {
        u16 hh = bf16_rtn(f[j]);
        h[j] = hh;
        l[j] = bf16_rtn(f[j] - bf16_up(hh));
    }
    ((u16x4*)hi)[i] = h;
    ((u16x4*)lo)[i] = l;
}

// ---------------------------------------------------------------------------
// QKV GEMM: X(4096x768 f32) * qkv_w^T (pre-split bf16 hi/lo).
// 128x128 tile, BK=32, 4 waves 2x2, split-bf16 3-term MFMA.
// A staged with in-kernel trunc-split; B via global_load_lds (fragment-linear).
// Epilogue: q (scaled by QSCALE) and k as bf16 hi/lo [bh][n][64];
//           v as single bf16 TRANSPOSED [bh][64][n].
// ---------------------------------------------------------------------------
__global__ __launch_bounds__(256) void gemm_qkv(const float* __restrict__ X,
                                                const u16* __restrict__ Wh,
                                                const u16* __restrict__ Wl,
                                                u16* __restrict__ qh, u16* __restrict__ ql,
                                                u16* __restrict__ kh, u16* __restrict__ kl,
                                                u16* __restrict__ vT) {
    __shared__ __align__(16) u16 sA[2][8][512];
    __shared__ __align__(16) u16 sB[2][8][512];

    const int tid = threadIdx.x, wave = tid >> 6, lane = tid & 63;
    const int g = lane >> 4, c = lane & 15;
    const int m0 = blockIdx.y * 128, c0 = blockIdx.x * 128;
    const int wm = wave >> 1, wn = wave & 1;

    f32x4 acc[4][4];
#pragma unroll
    for (int i = 0; i < 4; ++i)
#pragma unroll
        for (int j = 0; j < 4; ++j) acc[i][j] = (f32x4)(0.f);

    for (int k0 = 0; k0 < 768; k0 += 32) {
        __syncthreads();
        // B: async direct-to-LDS, 4 chunks per wave
#pragma unroll
        for (int qq = 0; qq < 4; ++qq) {
            const int idx = wave * 4 + qq;
            const int pl = idx >> 3, t = idx & 7;
            const u16* src = (pl ? Wl : Wh) + (size_t)(c0 + t * 16 + c) * 768 + k0 + g * 8;
            gld_lds16(src, &sB[pl][t][0]);
        }
        // A: f32 load + trunc-split (3 VALU/elem), 2 tiles per wave
#pragma unroll
        for (int tt = 0; tt < 2; ++tt) {
            const int t = wave * 2 + tt;
            const float* p = X + (size_t)(m0 + t * 16 + c) * 768 + k0 + g * 8;
            const float4 v0 = *(const float4*)p;
            const float4 v1 = *(const float4*)(p + 4);
            const float f[8] = {v0.x, v0.y, v0.z, v0.w, v1.x, v1.y, v1.z, v1.w};
            bf16x8 vh, vl;
#pragma unroll
            for (int e = 0; e < 8; ++e) {
                const u32 u = __builtin_bit_cast(u32, f[e]);
                const u16 hh = (u16)(u >> 16);
                const float r = f[e] - bf16_up(hh);
                vh[e] = (short)hh;
                vl[e] = (short)(__builtin_bit_cast(u32, r) >> 16);
            }
            *(bf16x8*)&sA[0][t][lane * 8] = vh;
            *(bf16x8*)&sA[1][t][lane * 8] = vl;
        }
        __syncthreads();

        bf16x8 Ah[4], Al[4], Bh[4], Bl[4];
#pragma unroll
        for (int i = 0; i < 4; ++i) {
            Ah[i] = *(const bf16x8*)&sA[0][wm * 4 + i][lane * 8];
            Al[i] = *(const bf16x8*)&sA[1][wm * 4 + i][lane * 8];
            Bh[i] = *(const bf16x8*)&sB[0][wn * 4 + i][lane * 8];
            Bl[i] = *(const bf16x8*)&sB[1][wn * 4 + i][lane * 8];
        }
#pragma unroll
        for (int i = 0; i < 4; ++i)
#pragma unroll
            for (int j = 0; j < 4; ++j) {
                acc[i][j] = __builtin_amdgcn_mfma_f32_16x16x32_bf16(Ah[i], Bh[j], acc[i][j], 0, 0, 0);
                acc[i][j] = __builtin_amdgcn_mfma_f32_16x16x32_bf16(Ah[i], Bl[j], acc[i][j], 0, 0, 0);
                acc[i][j] = __builtin_amdgcn_mfma_f32_16x16x32_bf16(Al[i], Bh[j], acc[i][j], 0, 0, 0);
            }
    }

    // Epilogue: D-frag row = g*4+r, col = c (verified round 2)
    const int b = m0 >> 10;
#pragma unroll
    for (int j = 0; j < 4; ++j) {
        const int cg = c0 + wn * 64 + j * 16;
        const int s = cg / 768;
        const int h = (cg % 768) / 64;
        const int d = (cg % 64) + c;
#pragma unroll
        for (int i = 0; i < 4; ++i) {
            const int nbase = (m0 & 1023) + wm * 64 + i * 16 + g * 4;
            if (s == 2) {
                u16x4 pk;
#pragma unroll
                for (int r = 0; r < 4; ++r) pk[r] = bf16_rtn(acc[i][j][r]);
                *(u16x4*)(vT + ((size_t)(b * HH + h) << 16) + (size_t)d * 1024 + nbase) = pk;
            } else {
                u16* dh = s ? kh : qh;
                u16* dl = s ? kl : ql;
                const float sc = s ? 1.0f : QSCALE;
#pragma unroll
                for (int r = 0; r < 4; ++r) {
                    const float vv = acc[i][j][r] * sc;
                    const u16 hh = bf16_rtn(vv);
                    const size_t a = ((size_t)(b * HH + h) * NN + nbase + r) * 64 + d;
                    dh[a] = hh;
                    dl[a] = bf16_rtn(vv - bf16_up(hh));
                }
            }
        }
    }
}

// ---------------------------------------------------------------------------
// Flash attention, MFMA. Block = (bh, 128-row q tile), 4 waves x 32 rows.
// S = split QK^T (3-term); P, V single bf16. KV tiles of 64 via global_load_lds.
// Base-2 softmax domain (Q pre-scaled by 0.125*log2e, tbl pre-scaled by log2e).
// ---------------------------------------------------------------------------
__global__ __launch_bounds__(256) void attn_mfma(const u16* __restrict__ qh_,
                                                 const u16* __restrict__ ql_,
                                                 const u16* __restrict__ kh_,
                                                 const u16* __restrict__ kl_,
                                                 const u16* __restrict__ vT,
                                                 const float* __restrict__ rel_table,
                                                 u16* __restrict__ attout) {
    __shared__ __align__(16) u16 sK[2][4][2][512];  // [pl][jn][ks] 16KB
    __shared__ __align__(16) u16 sV[4][2][512];     // [dj][ks]     8KB
    __shared__ __align__(16) u16 sP[4][32][72];     // per-wave P   18KB
    __shared__ float tbl[132];

    const int tid = threadIdx.x, wave = tid >> 6, lane = tid & 63;
    const int g = lane >> 4, c = lane & 15;
    // bh-major swizzle: the 8 q-blocks of one head land on one XCD (K/V L2-resident)
    const int bh = blockIdx.x % 48;
    const int q0 = (blockIdx.x / 48) * 128;
    const int b = bh / HH, h = bh % HH;

    if (tid < 129) tbl[tid] = rel_table[tid * HH + h] * 1.44269504f;

    // hoist Q fragments (rows q0+wave*32 .. +32)
    bf16x8 Qh[2][2], Ql[2][2];
#pragma unroll
    for (int rt = 0; rt < 2; ++rt)
#pragma unroll
        for (int ks = 0; ks < 2; ++ks) {
            const size_t a = ((size_t)bh * NN + q0 + wave * 32 + rt * 16 + c) * 64 + ks * 32 + g * 8;
            Qh[rt][ks] = *(const bf16x8*)(qh_ + a);
            Ql[rt][ks] = *(const bf16x8*)(ql_ + a);
        }

    f32x4 O[2][4];
    float mrun[2][4], lrun[2][4];
#pragma unroll
    for (int rt = 0; rt < 2; ++rt)
#pragma unroll
        for (int r = 0; r < 4; ++r) {
            mrun[rt][r] = -INFINITY;
            lrun[rt][r] = 0.f;
        }
#pragma unroll
    for (int rt = 0; rt < 2; ++rt)
#pragma unroll
        for (int dj = 0; dj < 4; ++dj) O[rt][dj] = (f32x4)(0.f);

    __syncthreads();  // tbl visible

    for (int t = 0; t < 16; ++t) {
        const int kv0 = t * 64;
        __syncthreads();  // prev tile's frag reads done
        // stage K(hi,lo) + V: 24 chunks, 6 per wave
#pragma unroll
        for (int qq = 0; qq < 6; ++qq) {
            const int idx = wave * 6 + qq;
            if (idx < 16) {
                const int pl = idx >> 3, rem = idx & 7, jn = rem >> 1, ks = rem & 1;
                const u16* src = (pl ? kl_ : kh_) + ((size_t)bh * NN + kv0 + jn * 16 + c) * 64 + ks * 32 + g * 8;
                gld_lds16(src, &sK[pl][jn][ks][0]);
            } else {
                const int rem = idx - 16, dj = rem >> 1, ks = rem & 1;
                const u16* src = vT + ((size_t)bh << 16) + (size_t)(dj * 16 + c) * 1024 + kv0 + ks * 32 + g * 8;
                gld_lds16(src, &sV[dj][ks][0]);
            }
        }
        __syncthreads();

        // S = QK^T (3-term split)
        f32x4 S[2][4];
#pragma unroll
        for (int rt = 0; rt < 2; ++rt)
#pragma unroll
            for (int jn = 0; jn < 4; ++jn) S[rt][jn] = (f32x4)(0.f);
#pragma unroll
        for (int jn = 0; jn < 4; ++jn)
#pragma unroll
            for (int ks = 0; ks < 2; ++ks) {
                const bf16x8 Kh_ = *(const bf16x8*)&sK[0][jn][ks][lane * 8];
                const bf16x8 Kl_ = *(const bf16x8*)&sK[1][jn][ks][lane * 8];
#pragma unroll
                for (int rt = 0; rt < 2; ++rt) {
                    S[rt][jn] = __builtin_amdgcn_mfma_f32_16x16x32_bf16(Qh[rt][ks], Kh_, S[rt][jn], 0, 0, 0);
                    S[rt][jn] = __builtin_amdgcn_mfma_f32_16x16x32_bf16(Qh[rt][ks], Kl_, S[rt][jn], 0, 0, 0);
                    S[rt][jn] = __builtin_amdgcn_mfma_f32_16x16x32_bf16(Ql[rt][ks], Kh_, S[rt][jn], 0, 0, 0);
                }
            }

        // + relative-position bias (log2 domain); wave-uniform clamp fast path
#pragma unroll
        for (int rt = 0; rt < 2; ++rt) {
            const int R0 = q0 + wave * 32 + rt * 16;
#pragma unroll
            for (int jn = 0; jn < 4; ++jn) {
                const int dd = (kv0 + jn * 16) - R0;
                if (dd <= -79) {
                    const float bv = tbl[0];
#pragma unroll
                    for (int r = 0; r < 4; ++r) S[rt][jn][r] += bv;
                } else if (dd >= 79) {
                    const float bv = tbl[128];
#pragma unroll
                    for (int r = 0; r < 4; ++r) S[rt][jn][r] += bv;
                } else {
#pragma unroll
                    for (int r = 0; r < 4; ++r) {
                        int off = dd + c - g * 4 - r + 64;
                        off = off < 0 ? 0 : (off > 128 ? 128 : off);
                        S[rt][jn][r] += tbl[off];
                    }
                }
            }
        }

        // online softmax (base 2); rows live on 16-lane c-groups
#pragma unroll
        for (int rt = 0; rt < 2; ++rt) {
#pragma unroll
            for (int r = 0; r < 4; ++r) {
                float mx = fmaxf(fmaxf(S[rt][0][r], S[rt][1][r]), fmaxf(S[rt][2][r], S[rt][3][r]));
                mx = fmaxf(mx, __shfl_xor(mx, 1));
                mx = fmaxf(mx, __shfl_xor(mx, 2));
                mx = fmaxf(mx, __shfl_xor(mx, 4));
                mx = fmaxf(mx, __shfl_xor(mx, 8));
                const float mnew = fmaxf(mrun[rt][r], mx);
                const float alpha = exp2f(mrun[rt][r] - mnew);
                mrun[rt][r] = mnew;
                float rs = 0.f;
#pragma unroll
                for (int jn = 0; jn < 4; ++jn) {
                    const float p = exp2f(S[rt][jn][r] - mnew);
                    S[rt][jn][r] = p;
                    rs += p;
                }
                rs += __shfl_xor(rs, 1);
                rs += __shfl_xor(rs, 2);
                rs += __shfl_xor(rs, 4);
                rs += __shfl_xor(rs, 8);
                lrun[rt][r] = lrun[rt][r] * alpha + rs;
#pragma unroll
                for (int dj = 0; dj < 4; ++dj) O[rt][dj][r] *= alpha;
            }
        }

        // P -> bf16, transpose through per-wave LDS (no barrier needed)
#pragma unroll
        for (int rt = 0; rt < 2; ++rt)
#pragma unroll
            for (int jn = 0; jn < 4; ++jn)
#pragma unroll
                for (int r = 0; r < 4; ++r)
                    sP[wave][rt * 16 + g * 4 + r][jn * 16 + c] = bf16_rtn(S[rt][jn][r]);

        // O += P V
#pragma unroll
        for (int ks = 0; ks < 2; ++ks) {
            const bf16x8 Pa0 = *(const bf16x8*)&sP[wave][c][ks * 32 + g * 8];
            const bf16x8 Pa1 = *(const bf16x8*)&sP[wave][16 + c][ks * 32 + g * 8];
#pragma unroll
            for (int dj = 0; dj < 4; ++dj) {
                const bf16x8 Vf = *(const bf16x8*)&sV[dj][ks][lane * 8];
                O[0][dj] = __builtin_amdgcn_mfma_f32_16x16x32_bf16(Pa0, Vf, O[0][dj], 0, 0, 0);
                O[1][dj] = __builtin_amdgcn_mfma_f32_16x16x32_bf16(Pa1, Vf, O[1][dj], 0, 0, 0);
            }
        }
    }

    // epilogue: normalize, write attout bf16 [b][n][768]
#pragma unroll
    for (int rt = 0; rt < 2; ++rt)
#pragma unroll
        for (int r = 0; r < 4; ++r) {
            const float inv = 1.0f / lrun[rt][r];
            const int n = q0 + wave * 32 + rt * 16 + g * 4 + r;
            u16* dst = attout + (size_t)(b * NN + n) * 768 + h * 64;
#pragma unroll
            for (int dj = 0; dj < 4; ++dj)
                dst[dj * 16 + c] = bf16_rtn(O[rt][dj][r] * inv);
        }
}

// ---------------------------------------------------------------------------
// Proj GEMM: attout(bf16 single) * proj_w^T (hi/lo) + bias -> f32 out.
// 2-term MFMA, all staging via global_load_lds.
// ---------------------------------------------------------------------------
__global__ __launch_bounds__(256) void gemm_proj(const u16* __restrict__ A,
                                                 const u16* __restrict__ Wh,
                                                 const u16* __restrict__ Wl,
                                                 const float* __restrict__ bias,
                                                 float* __restrict__ out) {
    __shared__ __align__(16) u16 sA[8][512];
    __shared__ __align__(16) u16 sB[2][8][512];

    const int tid = threadIdx.x, wave = tid >> 6, lane = tid & 63;
    const int g = lane >> 4, c = lane & 15;
    const int m0 = blockIdx.y * 128, c0 = blockIdx.x * 128;
    const int wm = wave >> 1, wn = wave & 1;

    f32x4 acc[4][4];
#pragma unroll
    for (int i = 0; i < 4; ++i)
#pragma unroll
        for (int j = 0; j < 4; ++j) acc[i][j] = (f32x4)(0.f);

    for (int k0 = 0; k0 < 768; k0 += 32) {
        __syncthreads();
#pragma unroll
        for (int qq = 0; qq < 6; ++qq) {
            const int idx = wave * 6 + qq;
            if (idx < 8) {
                const u16* src = A + (size_t)(m0 + idx * 16 + c) * 768 + k0 + g * 8;
                gld_lds16(src, &sA[idx][0]);
            } else {
                const int rem = idx - 8, pl = rem >> 3, tt = rem & 7;
                const u16* src = (pl ? Wl : Wh) + (size_t)(c0 + tt * 16 + c) * 768 + k0 + g * 8;
                gld_lds16(src, &sB[pl][tt][0]);
            }
        }
        __syncthreads();

        bf16x8 Aa[4], Bh[4], Bl[4];
#pragma unroll
        for (int i = 0; i < 4; ++i) {
            Aa[i] = *(const bf16x8*)&sA[wm * 4 + i][lane * 8];
            Bh[i] = *(const bf16x8*)&sB[0][wn * 4 + i][lane * 8];
            Bl[i] = *(const bf16x8*)&sB[1][wn * 4 + i][lane * 8];
        }
#pragma unroll
        for (int i = 0; i < 4; ++i)
#pragma unroll
            for (int j = 0; j < 4; ++j) {
                acc[i][j] = __builtin_amdgcn_mfma_f32_16x16x32_bf16(Aa[i], Bh[j], acc[i][j], 0, 0, 0);
                acc[i][j] = __builtin_amdgcn_mfma_f32_16x16x32_bf16(Aa[i], Bl[j], acc[i][j], 0, 0, 0);
            }
    }

#pragma unroll
    for (int j = 0; j < 4; ++j) {
        const int cg = c0 + wn * 64 + j * 16 + c;
        const float bv = bias[cg];
#pragma unroll
        for (int i = 0; i < 4; ++i)
#pragma unroll
            for (int r = 0; r < 4; ++r) {
                const int m = m0 + wm * 64 + i * 16 + g * 4 + r;
                out[(size_t)m * 768 + cg] = acc[i][j][r] + bv;
            }
    }
}

// ---------------------------------------------------------------------------
extern "C" void kernel_launch(void* const* d_in, const int* in_sizes, int n_in,
                              void* d_out, int out_size, void* d_ws, size_t ws_size,
                              hipStream_t stream) {
    const float* x = (const float*)d_in[0];
    const float* qkv_w = (const float*)d_in[1];
    const float* proj_w = (const float*)d_in[2];
    const float* proj_b = (const float*)d_in[3];
    const float* rel_table = (const float*)d_in[4];

    char* ws = (char*)d_ws;
    // byte offsets (peak 47.19 MB)
    u16* qkvwh = (u16*)(ws);                    // 3,538,944
    u16* qkvwl = (u16*)(ws + 3538944);          // 3,538,944
    u16* qh = (u16*)(ws + 7077888);             // 6,291,456
    u16* ql = (u16*)(ws + 13369344);
    u16* kh = (u16*)(ws + 19660800);
    u16* kl = (u16*)(ws + 25952256);
    u16* vT = (u16*)(ws + 32243712);            // 6,291,456 (single plane, transposed)
    u16* ao = (u16*)(ws + 38535168);            // attout bf16, 6,291,456
    u16* pwh = (u16*)(ws + 44826624);           // 1,179,648
    u16* pwl = (u16*)(ws + 46006272);           // 1,179,648 -> end 47,185,920

    // 1) presplit weights
    presplit<<<dim3(1728), 256, 0, stream>>>(qkv_w, qkvwh, qkvwl, 442368);
    presplit<<<dim3(576), 256, 0, stream>>>(proj_w, pwh, pwl, 147456);

    // 2) QKV projection -> q/k (hi/lo, q pre-scaled), vT (bf16, transposed)
    gemm_qkv<<<dim3(18, 32), 256, 0, stream>>>(x, qkvwh, qkvwl, qh, ql, kh, kl, vT);

    // 3) attention -> attout bf16
    attn_mfma<<<dim3(384), 256, 0, stream>>>(qh, ql, kh, kl, vT, rel_table, ao);

    // 4) output projection + bias -> f32
    gemm_proj<<<dim3(6, 32), 256, 0, stream>>>(ao, pwh, pwl, proj_b, (float*)d_out);
}